// Round 1
// baseline (1972.717 us; speedup 1.0000x reference)
//
#include <hip/hip_runtime.h>
#include <hip/hip_bf16.h>

// GraphSAGE 3-layer: 40 -> 64 -> 128 -> 3, mean aggregation over fixed edge set.
// Strategy: build CSR (dst -> list of src) once per call, then 3 fused
// (aggregate + lin_l + lin_r [+ relu]) kernels. No atomics in the hot loops.

static constexpr int NN = 100000;
static constexpr int EE = 1600000;

// ---------------- degree histogram ----------------
__global__ __launch_bounds__(256) void k_deg(const int* __restrict__ dst, int* __restrict__ deg) {
    int e = blockIdx.x * 256 + threadIdx.x;
    if (e < EE) atomicAdd(&deg[dst[e]], 1);
}

// ---------------- single-block exclusive scan (N=100k) + deg_inv ----------------
__global__ __launch_bounds__(1024) void k_scan(const int* __restrict__ deg, int* __restrict__ row_start,
                                               float* __restrict__ deg_inv) {
    const int tid = threadIdx.x;
    const int lane = tid & 63;
    const int wid = tid >> 6;          // 16 waves
    __shared__ int wave_sums[16];
    __shared__ int s_carry;
    if (tid == 0) s_carry = 0;
    __syncthreads();
    for (int base = 0; base < NN; base += 1024) {
        int i = base + tid;
        int v = (i < NN) ? deg[i] : 0;
        // inclusive scan within wave
        int inc = v;
#pragma unroll
        for (int d = 1; d < 64; d <<= 1) {
            int t = __shfl_up(inc, d, 64);
            if (lane >= d) inc += t;
        }
        if (lane == 63) wave_sums[wid] = inc;
        __syncthreads();
        if (wid == 0 && lane < 16) {
            int w = wave_sums[lane];
            int winc = w;
#pragma unroll
            for (int d = 1; d < 16; d <<= 1) {
                int t = __shfl_up(winc, d, 16);
                if (lane >= d) winc += t;
            }
            wave_sums[lane] = winc - w;   // exclusive wave offset
        }
        __syncthreads();
        int carry = s_carry;
        if (i < NN) {
            row_start[i] = carry + wave_sums[wid] + (inc - v);
            deg_inv[i] = (v > 0) ? 1.0f / (float)v : 0.0f;
        }
        __syncthreads();                   // everyone done reading s_carry/wave_sums
        if (tid == 1023) s_carry = carry + wave_sums[15] + inc;
        __syncthreads();
    }
    if (tid == 0) row_start[NN] = s_carry;
}

// ---------------- CSR scatter ----------------
__global__ __launch_bounds__(256) void k_fill(const int* __restrict__ src, const int* __restrict__ dst,
                                              const int* __restrict__ row_start, int* __restrict__ cursor,
                                              int* __restrict__ csr_src) {
    int e = blockIdx.x * 256 + threadIdx.x;
    if (e < EE) {
        int d = dst[e];
        int pos = atomicAdd(&cursor[d], 1);
        csr_src[row_start[d] + pos] = src[e];
    }
}

// ---------------- fused SAGE layer: mean-agg + Wl + Wr (+relu) ----------------
// One wave handles NPW nodes: stages mean & root rows to LDS, then a
// register-blocked GEMV (lane -> output feature, NPW accumulators) so weight
// rows are read once per NPW nodes instead of once per node.
template<int Fin, int Fout, bool RELU, int NPW>
__global__ __launch_bounds__(256) void k_layer(
    const float* __restrict__ xin, const float* __restrict__ Wl,
    const float* __restrict__ bias, const float* __restrict__ Wr,
    const int* __restrict__ row_start, const int* __restrict__ csr_src,
    const float* __restrict__ deg_inv, float* __restrict__ out) {
    constexpr int WPB = 4;  // waves per 256-thread block
    __shared__ float s_mean[WPB][NPW][Fin];
    __shared__ float s_root[WPB][NPW][Fin];
    const int lane = threadIdx.x & 63;
    const int wid = threadIdx.x >> 6;
    const int base = (blockIdx.x * WPB + wid) * NPW;
    if (base >= NN) return;

    // ---- stage: aggregate neighbors + root features into LDS (per-wave region) ----
    for (int j = 0; j < NPW; ++j) {
        int node = base + j;
        if (node >= NN) break;
        int rs = row_start[node], re = row_start[node + 1];
        float di = deg_inv[node];
        for (int f = lane; f < Fin; f += 64) {
            float acc = 0.f;
            for (int k = rs; k < re; ++k) {
                int s = csr_src[k];
                acc += xin[(size_t)s * Fin + f];
            }
            s_mean[wid][j][f] = acc * di;
            s_root[wid][j][f] = xin[(size_t)node * Fin + f];
        }
    }
    // per-wave LDS region: in-wave ordering suffices, no __syncthreads needed.

    // ---- GEMV: lane owns output features o, o+64, ... ----
    for (int o = lane; o < Fout; o += 64) {
        float acc[NPW];
        float bo = bias[o];
#pragma unroll
        for (int j = 0; j < NPW; ++j) acc[j] = bo;
        const float* wlr = Wl + (size_t)o * Fin;
        const float* wrr = Wr + (size_t)o * Fin;
        for (int f = 0; f < Fin; f += 4) {
            float4 wl4 = *(const float4*)(wlr + f);
            float4 wr4 = *(const float4*)(wrr + f);
#pragma unroll
            for (int j = 0; j < NPW; ++j) {
                acc[j] += s_mean[wid][j][f + 0] * wl4.x + s_mean[wid][j][f + 1] * wl4.y
                        + s_mean[wid][j][f + 2] * wl4.z + s_mean[wid][j][f + 3] * wl4.w
                        + s_root[wid][j][f + 0] * wr4.x + s_root[wid][j][f + 1] * wr4.y
                        + s_root[wid][j][f + 2] * wr4.z + s_root[wid][j][f + 3] * wr4.w;
            }
        }
#pragma unroll
        for (int j = 0; j < NPW; ++j) {
            int node = base + j;
            if (node < NN) {
                float v = acc[j];
                if (RELU) v = fmaxf(v, 0.f);
                out[(size_t)node * Fout + o] = v;
            }
        }
    }
}

// ---------------- layer 3 (Fout=3): wave per node, feature-parallel + shuffle reduce ----
__global__ __launch_bounds__(256) void k_layer3(
    const float* __restrict__ h2, const float* __restrict__ W4l,
    const float* __restrict__ b4, const float* __restrict__ W4r,
    const int* __restrict__ row_start, const int* __restrict__ csr_src,
    const float* __restrict__ deg_inv, float* __restrict__ out) {
    const int lane = threadIdx.x & 63;
    const int node = (blockIdx.x * blockDim.x + threadIdx.x) >> 6;
    if (node >= NN) return;
    const int f0 = lane, f1 = lane + 64;
    int rs = row_start[node], re = row_start[node + 1];
    float a0 = 0.f, a1 = 0.f;
    for (int k = rs; k < re; ++k) {
        int s = csr_src[k];
        a0 += h2[(size_t)s * 128 + f0];
        a1 += h2[(size_t)s * 128 + f1];
    }
    float di = deg_inv[node];
    float m0 = a0 * di, m1 = a1 * di;
    float r0 = h2[(size_t)node * 128 + f0], r1 = h2[(size_t)node * 128 + f1];
    float p0 = m0 * W4l[0 * 128 + f0] + m1 * W4l[0 * 128 + f1] + r0 * W4r[0 * 128 + f0] + r1 * W4r[0 * 128 + f1];
    float p1 = m0 * W4l[1 * 128 + f0] + m1 * W4l[1 * 128 + f1] + r0 * W4r[1 * 128 + f0] + r1 * W4r[1 * 128 + f1];
    float p2 = m0 * W4l[2 * 128 + f0] + m1 * W4l[2 * 128 + f1] + r0 * W4r[2 * 128 + f0] + r1 * W4r[2 * 128 + f1];
#pragma unroll
    for (int d = 32; d; d >>= 1) {
        p0 += __shfl_down(p0, d, 64);
        p1 += __shfl_down(p1, d, 64);
        p2 += __shfl_down(p2, d, 64);
    }
    if (lane == 0) {
        out[(size_t)node * 3 + 0] = p0 + b4[0];
        out[(size_t)node * 3 + 1] = p1 + b4[1];
        out[(size_t)node * 3 + 2] = p2 + b4[2];
    }
}

extern "C" void kernel_launch(void* const* d_in, const int* in_sizes, int n_in,
                              void* d_out, int out_size, void* d_ws, size_t ws_size,
                              hipStream_t stream) {
    const float* x   = (const float*)d_in[0];
    const int*   ei  = (const int*)d_in[1];          // [2, E] int32: row0=src, row1=dst
    const float* W1l = (const float*)d_in[2];
    const float* b1  = (const float*)d_in[3];
    const float* W1r = (const float*)d_in[4];
    const float* W2l = (const float*)d_in[5];
    const float* b2  = (const float*)d_in[6];
    const float* W2r = (const float*)d_in[7];
    const float* W4l = (const float*)d_in[8];
    const float* b4  = (const float*)d_in[9];
    const float* W4r = (const float*)d_in[10];
    float* out = (float*)d_out;

    char* ws = (char*)d_ws;
    size_t off = 0;
    auto alloc = [&](size_t bytes) -> void* {
        void* p = ws + off;
        off = (off + bytes + 255) & ~(size_t)255;
        return p;
    };
    int*   deg       = (int*)alloc((size_t)NN * 4);
    int*   row_start = (int*)alloc(((size_t)NN + 1) * 4);
    int*   cursor    = (int*)alloc((size_t)NN * 4);
    int*   csr_src   = (int*)alloc((size_t)EE * 4);
    float* deg_inv   = (float*)alloc((size_t)NN * 4);
    float* h1        = (float*)alloc((size_t)NN * 64 * 4);
    float* h2        = (float*)alloc((size_t)NN * 128 * 4);

    const int* e_src = ei;
    const int* e_dst = ei + EE;

    hipMemsetAsync(deg, 0, (size_t)NN * 4, stream);
    hipMemsetAsync(cursor, 0, (size_t)NN * 4, stream);

    k_deg<<<(EE + 255) / 256, 256, 0, stream>>>(e_dst, deg);
    k_scan<<<1, 1024, 0, stream>>>(deg, row_start, deg_inv);
    k_fill<<<(EE + 255) / 256, 256, 0, stream>>>(e_src, e_dst, row_start, cursor, csr_src);

    constexpr int NPW = 8;
    int waves = (NN + NPW - 1) / NPW;
    int blocks = (waves + 3) / 4;
    k_layer<40, 64, true, NPW><<<blocks, 256, 0, stream>>>(x, W1l, b1, W1r, row_start, csr_src, deg_inv, h1);
    k_layer<64, 128, true, NPW><<<blocks, 256, 0, stream>>>(h1, W2l, b2, W2r, row_start, csr_src, deg_inv, h2);
    k_layer3<<<((size_t)NN * 64 + 255) / 256, 256, 0, stream>>>(h2, W4l, b4, W4r, row_start, csr_src, deg_inv, out);
}

// Round 2
// 670.343 us; speedup vs baseline: 2.9428x; 2.9428x over previous
//
#include <hip/hip_runtime.h>
#include <hip/hip_bf16.h>

// GraphSAGE 3-layer: 40 -> 64 -> 128 -> 3, mean aggregation over fixed edges.
// R2: split aggregate/transform (R1's fused k_layer hit VGPR=256 + scratch
// spills -> 456MB write traffic, 1075us). Layer 3 uses transform-before-gather
// (mean commutes with linear): gather 12B/edge instead of 512B/edge.

static constexpr int NN = 100000;
static constexpr int EE = 1600000;
static constexpr int NB = (NN + 255) / 256;   // 391 scan blocks

// ---------------- degree histogram ----------------
__global__ __launch_bounds__(256) void k_deg(const int* __restrict__ dst, int* __restrict__ deg) {
    int e = blockIdx.x * 256 + threadIdx.x;
    if (e < EE) atomicAdd(&deg[dst[e]], 1);
}

// ---------------- hierarchical scan: block sums ----------------
__global__ __launch_bounds__(256) void k_bsum(const int* __restrict__ deg, int* __restrict__ bsum) {
    int i = blockIdx.x * 256 + threadIdx.x;
    int v = (i < NN) ? deg[i] : 0;
    int lane = threadIdx.x & 63, wid = threadIdx.x >> 6;
#pragma unroll
    for (int d = 32; d; d >>= 1) v += __shfl_down(v, d, 64);
    __shared__ int wsum[4];
    if (lane == 0) wsum[wid] = v;
    __syncthreads();
    if (threadIdx.x == 0) bsum[blockIdx.x] = wsum[0] + wsum[1] + wsum[2] + wsum[3];
}

// ---------------- scan of 391 block sums (one block) ----------------
__global__ __launch_bounds__(512) void k_bscan(const int* __restrict__ bsum, int* __restrict__ boff,
                                               int* __restrict__ row_start) {
    __shared__ int s[512];
    int tid = threadIdx.x;
    int v = (tid < NB) ? bsum[tid] : 0;
    s[tid] = v;
    __syncthreads();
    for (int d = 1; d < 512; d <<= 1) {
        int t = (tid >= d) ? s[tid - d] : 0;
        __syncthreads();
        s[tid] += t;
        __syncthreads();
    }
    if (tid < NB) boff[tid] = s[tid] - v;   // exclusive
    if (tid == 0) row_start[NN] = EE;
}

// ---------------- final scan: row_start + deg_inv ----------------
__global__ __launch_bounds__(256) void k_scan2(const int* __restrict__ deg, const int* __restrict__ boff,
                                               int* __restrict__ row_start, float* __restrict__ deg_inv) {
    int tid = threadIdx.x, lane = tid & 63, wid = tid >> 6;
    int i = blockIdx.x * 256 + tid;
    int v = (i < NN) ? deg[i] : 0;
    int inc = v;
#pragma unroll
    for (int d = 1; d < 64; d <<= 1) {
        int t = __shfl_up(inc, d, 64);
        if (lane >= d) inc += t;
    }
    __shared__ int wsum[4];
    if (lane == 63) wsum[wid] = inc;
    __syncthreads();
    if (tid == 0) {
        int s = 0;
#pragma unroll
        for (int j = 0; j < 4; ++j) { int t = wsum[j]; wsum[j] = s; s += t; }
    }
    __syncthreads();
    if (i < NN) {
        row_start[i] = boff[blockIdx.x] + wsum[wid] + (inc - v);
        deg_inv[i] = (v > 0) ? 1.0f / (float)v : 0.0f;
    }
}

// ---------------- CSR scatter ----------------
__global__ __launch_bounds__(256) void k_fill(const int* __restrict__ src, const int* __restrict__ dst,
                                              const int* __restrict__ row_start, int* __restrict__ cursor,
                                              int* __restrict__ csr_src) {
    int e = blockIdx.x * 256 + threadIdx.x;
    if (e < EE) {
        int d = dst[e];
        int pos = atomicAdd(&cursor[d], 1);
        csr_src[row_start[d] + pos] = src[e];
    }
}

// ---------------- mean aggregation: 16 lanes/node, float4/lane ----------------
template<int F>
__global__ __launch_bounds__(256) void k_mean4(const float* __restrict__ xin,
                                               const int* __restrict__ row_start,
                                               const int* __restrict__ csr_src,
                                               const float* __restrict__ deg_inv,
                                               float* __restrict__ mean) {
    int gid = blockIdx.x * 256 + threadIdx.x;
    int node = gid >> 4;
    int fq = (gid & 15) * 4;
    if (node >= NN) return;
    if (fq >= F) return;                     // F=40: lanes 10..15 of group idle
    int rs = row_start[node], re = row_start[node + 1];
    float a0x = 0, a0y = 0, a0z = 0, a0w = 0;
    float a1x = 0, a1y = 0, a1z = 0, a1w = 0;
    float a2x = 0, a2y = 0, a2z = 0, a2w = 0;
    float a3x = 0, a3y = 0, a3z = 0, a3w = 0;
    int k = rs;
    for (; k + 4 <= re; k += 4) {
        int s0 = csr_src[k], s1 = csr_src[k + 1], s2 = csr_src[k + 2], s3 = csr_src[k + 3];
        float4 v0 = *(const float4*)&xin[(size_t)s0 * F + fq];
        float4 v1 = *(const float4*)&xin[(size_t)s1 * F + fq];
        float4 v2 = *(const float4*)&xin[(size_t)s2 * F + fq];
        float4 v3 = *(const float4*)&xin[(size_t)s3 * F + fq];
        a0x += v0.x; a0y += v0.y; a0z += v0.z; a0w += v0.w;
        a1x += v1.x; a1y += v1.y; a1z += v1.z; a1w += v1.w;
        a2x += v2.x; a2y += v2.y; a2z += v2.z; a2w += v2.w;
        a3x += v3.x; a3y += v3.y; a3z += v3.z; a3w += v3.w;
    }
    for (; k < re; ++k) {
        float4 v0 = *(const float4*)&xin[(size_t)csr_src[k] * F + fq];
        a0x += v0.x; a0y += v0.y; a0z += v0.z; a0w += v0.w;
    }
    float di = deg_inv[node];
    float4 m;
    m.x = (a0x + a1x + a2x + a3x) * di;
    m.y = (a0y + a1y + a2y + a3y) * di;
    m.z = (a0z + a1z + a2z + a3z) * di;
    m.w = (a0w + a1w + a2w + a3w) * di;
    *(float4*)&mean[(size_t)node * F + fq] = m;
}

// ---------------- linear: out[n, obase+lane] = mean@Wl.T + b + root@Wr.T ----------------
// 64 outputs per block (blockIdx.y selects which 64 of FoutT). Weights staged
// transposed in LDS with pitch 65 (conflict-free stage + read). 4 nodes/wave.
template<int Fin, int FoutT, bool RELU>
__global__ __launch_bounds__(256) void k_lin(
    const float* __restrict__ mean, const float* __restrict__ root,
    const float* __restrict__ Wl, const float* __restrict__ bias, const float* __restrict__ Wr,
    float* __restrict__ out) {
    __shared__ float sWl[Fin * 65];
    __shared__ float sWr[Fin * 65];
    const int obase = blockIdx.y * 64;
    for (int idx = threadIdx.x; idx < Fin * 64; idx += 256) {
        int o = idx / Fin, f = idx % Fin;                 // coalesced global read
        sWl[f * 65 + o] = Wl[(size_t)obase * Fin + idx];  // stride-65 write: no conflict
        sWr[f * 65 + o] = Wr[(size_t)obase * Fin + idx];
    }
    __syncthreads();
    const int lane = threadIdx.x & 63;
    const int wid = threadIdx.x >> 6;
    const float bo = bias[obase + lane];
    const int groups = NN / 4;                            // 100000 % 4 == 0
    for (int g = blockIdx.x * 4 + wid; g < groups; g += gridDim.x * 4) {
        int n0 = g * 4;
        float acc0 = bo, acc1 = bo, acc2 = bo, acc3 = bo;
        for (int f = 0; f < Fin; f += 4) {
            float4 m0 = *(const float4*)&mean[(size_t)(n0 + 0) * Fin + f];
            float4 m1 = *(const float4*)&mean[(size_t)(n0 + 1) * Fin + f];
            float4 m2 = *(const float4*)&mean[(size_t)(n0 + 2) * Fin + f];
            float4 m3 = *(const float4*)&mean[(size_t)(n0 + 3) * Fin + f];
            float4 r0 = *(const float4*)&root[(size_t)(n0 + 0) * Fin + f];
            float4 r1 = *(const float4*)&root[(size_t)(n0 + 1) * Fin + f];
            float4 r2 = *(const float4*)&root[(size_t)(n0 + 2) * Fin + f];
            float4 r3 = *(const float4*)&root[(size_t)(n0 + 3) * Fin + f];
#define SAGE_STEP(FF, C) { \
            float wl = sWl[(f + FF) * 65 + lane]; \
            float wr = sWr[(f + FF) * 65 + lane]; \
            acc0 += m0.C * wl + r0.C * wr; \
            acc1 += m1.C * wl + r1.C * wr; \
            acc2 += m2.C * wl + r2.C * wr; \
            acc3 += m3.C * wl + r3.C * wr; }
            SAGE_STEP(0, x) SAGE_STEP(1, y) SAGE_STEP(2, z) SAGE_STEP(3, w)
#undef SAGE_STEP
        }
        if (RELU) {
            acc0 = fmaxf(acc0, 0.f); acc1 = fmaxf(acc1, 0.f);
            acc2 = fmaxf(acc2, 0.f); acc3 = fmaxf(acc3, 0.f);
        }
        out[(size_t)(n0 + 0) * FoutT + obase + lane] = acc0;
        out[(size_t)(n0 + 1) * FoutT + obase + lane] = acc1;
        out[(size_t)(n0 + 2) * FoutT + obase + lane] = acc2;
        out[(size_t)(n0 + 3) * FoutT + obase + lane] = acc3;
    }
}

// ---------------- layer 3 transforms: z = h2@W4l.T, r = h2@W4r.T (no bias) ----------------
__global__ __launch_bounds__(256) void k_zr(const float* __restrict__ h2,
                                            const float* __restrict__ W4l, const float* __restrict__ W4r,
                                            float* __restrict__ z, float* __restrict__ r) {
    int node = (blockIdx.x * 256 + threadIdx.x) >> 6;
    int lane = threadIdx.x & 63;
    if (node >= NN) return;
    float h0 = h2[(size_t)node * 128 + lane];
    float h1v = h2[(size_t)node * 128 + 64 + lane];
    float zc0 = h0 * W4l[0 * 128 + lane] + h1v * W4l[0 * 128 + 64 + lane];
    float zc1 = h0 * W4l[1 * 128 + lane] + h1v * W4l[1 * 128 + 64 + lane];
    float zc2 = h0 * W4l[2 * 128 + lane] + h1v * W4l[2 * 128 + 64 + lane];
    float rc0 = h0 * W4r[0 * 128 + lane] + h1v * W4r[0 * 128 + 64 + lane];
    float rc1 = h0 * W4r[1 * 128 + lane] + h1v * W4r[1 * 128 + 64 + lane];
    float rc2 = h0 * W4r[2 * 128 + lane] + h1v * W4r[2 * 128 + 64 + lane];
#pragma unroll
    for (int d = 32; d; d >>= 1) {
        zc0 += __shfl_down(zc0, d, 64); zc1 += __shfl_down(zc1, d, 64); zc2 += __shfl_down(zc2, d, 64);
        rc0 += __shfl_down(rc0, d, 64); rc1 += __shfl_down(rc1, d, 64); rc2 += __shfl_down(rc2, d, 64);
    }
    if (lane == 0) {
        z[(size_t)node * 3 + 0] = zc0; z[(size_t)node * 3 + 1] = zc1; z[(size_t)node * 3 + 2] = zc2;
        r[(size_t)node * 3 + 0] = rc0; r[(size_t)node * 3 + 1] = rc1; r[(size_t)node * 3 + 2] = rc2;
    }
}

// ---------------- final: out = mean(z)[n] + r[n] + b4 ----------------
__global__ __launch_bounds__(256) void k_final(const float* __restrict__ z, const float* __restrict__ r,
                                               const float* __restrict__ b4,
                                               const int* __restrict__ row_start, const int* __restrict__ csr_src,
                                               const float* __restrict__ deg_inv, float* __restrict__ out) {
    int n = blockIdx.x * 256 + threadIdx.x;
    if (n >= NN) return;
    int rs = row_start[n], re = row_start[n + 1];
    float a0 = 0, a1 = 0, a2 = 0, b0 = 0, b1 = 0, b2 = 0;
    int k = rs;
    for (; k + 2 <= re; k += 2) {
        int s0 = csr_src[k], s1 = csr_src[k + 1];
        a0 += z[3 * (size_t)s0 + 0]; a1 += z[3 * (size_t)s0 + 1]; a2 += z[3 * (size_t)s0 + 2];
        b0 += z[3 * (size_t)s1 + 0]; b1 += z[3 * (size_t)s1 + 1]; b2 += z[3 * (size_t)s1 + 2];
    }
    if (k < re) {
        int s0 = csr_src[k];
        a0 += z[3 * (size_t)s0 + 0]; a1 += z[3 * (size_t)s0 + 1]; a2 += z[3 * (size_t)s0 + 2];
    }
    float di = deg_inv[n];
    out[(size_t)n * 3 + 0] = (a0 + b0) * di + r[(size_t)n * 3 + 0] + b4[0];
    out[(size_t)n * 3 + 1] = (a1 + b1) * di + r[(size_t)n * 3 + 1] + b4[1];
    out[(size_t)n * 3 + 2] = (a2 + b2) * di + r[(size_t)n * 3 + 2] + b4[2];
}

extern "C" void kernel_launch(void* const* d_in, const int* in_sizes, int n_in,
                              void* d_out, int out_size, void* d_ws, size_t ws_size,
                              hipStream_t stream) {
    const float* x   = (const float*)d_in[0];
    const int*   ei  = (const int*)d_in[1];
    const float* W1l = (const float*)d_in[2];
    const float* b1  = (const float*)d_in[3];
    const float* W1r = (const float*)d_in[4];
    const float* W2l = (const float*)d_in[5];
    const float* b2  = (const float*)d_in[6];
    const float* W2r = (const float*)d_in[7];
    const float* W4l = (const float*)d_in[8];
    const float* b4  = (const float*)d_in[9];
    const float* W4r = (const float*)d_in[10];
    float* out = (float*)d_out;

    char* ws = (char*)d_ws;
    size_t off = 0;
    auto alloc = [&](size_t bytes) -> void* {
        void* p = ws + off;
        off = (off + bytes + 255) & ~(size_t)255;
        return p;
    };
    int*   deg       = (int*)alloc((size_t)NN * 4);
    int*   row_start = (int*)alloc(((size_t)NN + 1) * 4);
    int*   cursor    = (int*)alloc((size_t)NN * 4);
    int*   csr_src   = (int*)alloc((size_t)EE * 4);
    float* deg_inv   = (float*)alloc((size_t)NN * 4);
    int*   bsum      = (int*)alloc((size_t)NB * 4);
    int*   boff      = (int*)alloc((size_t)NB * 4);
    float* h1        = (float*)alloc((size_t)NN * 64 * 4);
    float* h2        = (float*)alloc((size_t)NN * 128 * 4);
    float* scratch   = (float*)alloc((size_t)NN * 64 * 4);  // mean1 / mean2 / z+r (reused)
    float* mean1 = scratch;                 // N x 40
    float* mean2 = scratch;                 // N x 64  (after mean1 dead)
    float* zbuf  = scratch;                 // N x 3   (after mean2 dead)
    float* rbuf  = scratch + (size_t)NN * 3;

    const int* e_src = ei;
    const int* e_dst = ei + EE;

    hipMemsetAsync(deg, 0, (size_t)NN * 4, stream);
    hipMemsetAsync(cursor, 0, (size_t)NN * 4, stream);

    k_deg<<<(EE + 255) / 256, 256, 0, stream>>>(e_dst, deg);
    k_bsum<<<NB, 256, 0, stream>>>(deg, bsum);
    k_bscan<<<1, 512, 0, stream>>>(bsum, boff, row_start);
    k_scan2<<<NB, 256, 0, stream>>>(deg, boff, row_start, deg_inv);
    k_fill<<<(EE + 255) / 256, 256, 0, stream>>>(e_src, e_dst, row_start, cursor, csr_src);

    const int mean_blocks = ((size_t)NN * 16 + 255) / 256;   // 6250

    // layer 1: 40 -> 64
    k_mean4<40><<<mean_blocks, 256, 0, stream>>>(x, row_start, csr_src, deg_inv, mean1);
    k_lin<40, 64, true><<<dim3(512, 1), 256, 0, stream>>>(mean1, x, W1l, b1, W1r, h1);

    // layer 2: 64 -> 128
    k_mean4<64><<<mean_blocks, 256, 0, stream>>>(h1, row_start, csr_src, deg_inv, mean2);
    k_lin<64, 128, true><<<dim3(512, 2), 256, 0, stream>>>(mean2, h1, W2l, b2, W2r, h2);

    // layer 3: 128 -> 3, transform-before-gather
    k_zr<<<((size_t)NN * 64 + 255) / 256, 256, 0, stream>>>(h2, W4l, W4r, zbuf, rbuf);
    k_final<<<(NN + 255) / 256, 256, 0, stream>>>(zbuf, rbuf, b4, row_start, csr_src, deg_inv, out);
}